// Round 1
// baseline (467.223 us; speedup 1.0000x reference)
//
#include <hip/hip_runtime.h>
#include <hip/hip_bf16.h>
#include <math.h>

#define NH     4
#define RD     5
#define WW     49
#define DM     256
#define BATCH  32
#define NTOK   4900
#define GSEG   20
#define SEG    245            // WW*RD tokens per segment

typedef short bf16x8 __attribute__((ext_vector_type(8)));
typedef short bf16x4 __attribute__((ext_vector_type(4)));
typedef float f32x4  __attribute__((ext_vector_type(4)));

__device__ __forceinline__ short f2bf(float f) {
    union { __hip_bfloat16 h; short s; } u;
    u.h = __float2bfloat16(f);
    return u.s;
}

// Swizzled LDS index helpers (all XOR on 8-short granules -> b128-safe).
__device__ __forceinline__ int qix(int row, int col) {           // q tile, pitch 256
    return row * 256 + (col ^ ((row & 7) << 3));
}
__device__ __forceinline__ int xix(int d, int j) {               // XT, pitch 64
    return d * 64 + (j ^ ((((d >> 3) ^ d) & 7) << 3));
}
__device__ __forceinline__ int pix(int i, int j) {               // P, pitch 64
    return i * 64 + (j ^ ((i & 7) << 3));
}

// ---------------------------------------------------------------------------
// Pre-convert Wq, Wo (fp32 [256,256]) to bf16.
// ---------------------------------------------------------------------------
__global__ __launch_bounds__(256)
void wcvt(const float* __restrict__ Wq, const float* __restrict__ Wo,
          short* __restrict__ Wqb, short* __restrict__ Wob) {
    int t = blockIdx.x * 256 + threadIdx.x;       // 0..32767 float4 units
    const float* src = (t < 16384) ? Wq : Wo;
    short* dst = (t < 16384) ? Wqb : Wob;
    int i = (t & 16383) * 4;
    float4 v = *(const float4*)(src + i);
    bf16x4 o = { f2bf(v.x), f2bf(v.y), f2bf(v.z), f2bf(v.w) };
    *(bf16x4*)(dst + i) = o;
}

// ---------------------------------------------------------------------------
// Fused: one block per (b,g) segment. 512 threads = 8 waves.
//   Phase 1: q = bf16(emb @ Wq^T + bq)  -> LDS (window-permuted rows, swizzled)
//   Phase 2: 20 dilated-window attention groups in LDS, O overwrites q
//   Phase 3: out = O @ Wo^T + bo        -> global fp32
// LDS: q 245*256*2 = 125440 B + 2*XT(8KB) + 2*P(8KB) = 158208 B -> 1 block/CU.
// ---------------------------------------------------------------------------
__global__ __launch_bounds__(512, 2)
void fused(const float* __restrict__ emb, const short* __restrict__ Wqb,
           const float* __restrict__ bq, const short* __restrict__ Wob,
           const float* __restrict__ bo, float* __restrict__ out) {
    __shared__ __align__(16) short smem[SEG * DM + 4 * 4096];
    short* q_s = smem;

    const int tid = threadIdx.x;
    const int wv = tid >> 6, ln = tid & 63, lc = ln & 15, lq = ln >> 4;
    const int b = blockIdx.x / GSEG, g = blockIdx.x % GSEG;
    const size_t ebase = ((size_t)b * NTOK + (size_t)g * SEG) * DM;

    const int wm = (wv & 3) * 64;        // 4 M-strips of 64 rows
    const int wn = (wv >> 2) * 128;      // 2 N-halves of 128 cols

    // ================= Phase 1: q = bf16(emb @ Wq^T + bq) -> LDS =================
    {
        const float* ar[4];
        const short* br[8];
        #pragma unroll
        for (int mi = 0; mi < 4; mi++) {
            int t = wm + mi * 16 + lc;
            t = (t > SEG - 1) ? (SEG - 1) : t;          // clamp pad rows (masked later)
            ar[mi] = emb + ebase + (size_t)t * DM + lq * 8;
        }
        #pragma unroll
        for (int ni = 0; ni < 8; ni++)
            br[ni] = Wqb + (size_t)(wn + ni * 16 + lc) * DM + lq * 8;

        f32x4 acc[4][8] = {};
        for (int k0 = 0; k0 < DM; k0 += 32) {
            bf16x8 af[4], bfr[8];
            #pragma unroll
            for (int mi = 0; mi < 4; mi++) {
                float4 v0 = *(const float4*)(ar[mi] + k0);
                float4 v1 = *(const float4*)(ar[mi] + k0 + 4);
                bf16x8 t8 = { f2bf(v0.x), f2bf(v0.y), f2bf(v0.z), f2bf(v0.w),
                              f2bf(v1.x), f2bf(v1.y), f2bf(v1.z), f2bf(v1.w) };
                af[mi] = t8;
            }
            #pragma unroll
            for (int ni = 0; ni < 8; ni++) bfr[ni] = *(const bf16x8*)(br[ni] + k0);
            #pragma unroll
            for (int mi = 0; mi < 4; mi++)
                #pragma unroll
                for (int ni = 0; ni < 8; ni++)
                    acc[mi][ni] = __builtin_amdgcn_mfma_f32_16x16x32_bf16(
                        af[mi], bfr[ni], acc[mi][ni], 0, 0, 0);
        }
        float bv[8];
        #pragma unroll
        for (int ni = 0; ni < 8; ni++) bv[ni] = bq[wn + ni * 16 + lc];
        #pragma unroll
        for (int mi = 0; mi < 4; mi++)
            #pragma unroll
            for (int rg = 0; rg < 4; rg++) {
                const int t = wm + mi * 16 + lq * 4 + rg;
                if (t < SEG) {
                    // window-permuted row: tokens sharing (r) become contiguous
                    const int lr = (t % RD) * WW + t / RD;
                    #pragma unroll
                    for (int ni = 0; ni < 8; ni++)
                        q_s[qix(lr, wn + ni * 16 + lc)] =
                            f2bf(acc[mi][ni][rg] + bv[ni]);
                }
            }
    }
    __syncthreads();

    // ================= Phase 2: attention in LDS =================
    // 2 teams x 4 waves, 10 lockstep rounds; round rr: team tm does group
    // gi = 2*rr + tm -> (r = gi>>2, h = gi&3). Pairs within a round share r,
    // differ in h -> all q_s writes are (row, col)-disjoint across teams.
    {
        const int tm = wv >> 2, tv = wv & 3, ttid = tid & 255;
        short* xt = smem + SEG * DM + tm * 4096;          // [64 d][64 j] swizzled
        short* sp = smem + SEG * DM + 8192 + tm * 4096;   // [64 i][64 j] swizzled
        for (int rr = 0; rr < 10; rr++) {
            const int gi = rr * 2 + tm, r = gi >> 2, c0 = (gi & 3) * 64;

            // ---- (a) build XT[d][j] = X[j][d]; zeros for j >= 49 (NaN guard) ----
            #pragma unroll
            for (int u0 = 0; u0 < 2; u0++) {
                const int u = ttid + u0 * 256, j = u >> 3, dc = (u & 7) * 8;
                bf16x8 v = (bf16x8){0, 0, 0, 0, 0, 0, 0, 0};
                if (j < WW) v = *(const bf16x8*)&q_s[qix(r * WW + j, c0 + dc)];
                #pragma unroll
                for (int e = 0; e < 8; e++) xt[xix(dc + e, j)] = v[e];
            }
            // ---- (a) S = X·X^T (wave tv: rows tv*16..+15, all 64 cols) ----
            f32x4 sa[4] = {};
            {
                const int arw = r * WW + tv * 16 + lc;   // rows>=245 read garbage, masked
                const bf16x8 a0 = *(const bf16x8*)&q_s[qix(arw, c0 + lq * 8)];
                const bf16x8 a1 = *(const bf16x8*)&q_s[qix(arw, c0 + 32 + lq * 8)];
                #pragma unroll
                for (int ni = 0; ni < 4; ni++) {
                    const int brw = r * WW + ni * 16 + lc;
                    const bf16x8 b0 = *(const bf16x8*)&q_s[qix(brw, c0 + lq * 8)];
                    const bf16x8 b1 = *(const bf16x8*)&q_s[qix(brw, c0 + 32 + lq * 8)];
                    sa[ni] = __builtin_amdgcn_mfma_f32_16x16x32_bf16(a0, b0, sa[ni], 0, 0, 0);
                    sa[ni] = __builtin_amdgcn_mfma_f32_16x16x32_bf16(a1, b1, sa[ni], 0, 0, 0);
                }
            }
            __syncthreads();   // XT + all X reads complete before P/PV/O

            // ---- (b) softmax -> P (bf16, LDS) ----
            #pragma unroll
            for (int rg = 0; rg < 4; rg++) {
                float s[4];
                float m = -1e30f;
                #pragma unroll
                for (int ni = 0; ni < 4; ni++) {
                    s[ni] = sa[ni][rg] * 0.125f;          // 1/sqrt(64)
                    if (ni * 16 + lc < WW) m = fmaxf(m, s[ni]);
                }
                m = fmaxf(m, __shfl_xor(m, 1));
                m = fmaxf(m, __shfl_xor(m, 2));
                m = fmaxf(m, __shfl_xor(m, 4));
                m = fmaxf(m, __shfl_xor(m, 8));
                float e4[4], l_ = 0.f;
                #pragma unroll
                for (int ni = 0; ni < 4; ni++) {
                    e4[ni] = (ni * 16 + lc < WW) ? __expf(s[ni] - m) : 0.f;
                    l_ += e4[ni];
                }
                l_ += __shfl_xor(l_, 1);
                l_ += __shfl_xor(l_, 2);
                l_ += __shfl_xor(l_, 4);
                l_ += __shfl_xor(l_, 8);
                const float inv = 1.f / l_;
                const int pr = tv * 16 + lq * 4 + rg;
                #pragma unroll
                for (int ni = 0; ni < 4; ni++)
                    sp[pix(pr, ni * 16 + lc)] = f2bf(e4[ni] * inv);
            }
            // ---- (b) O = P·X  (A: wave-local P rows; intra-wave LDS order is safe) ----
            f32x4 oa[4] = {};
            {
                const int arw = tv * 16 + lc;
                const bf16x8 a0 = *(const bf16x8*)&sp[pix(arw, lq * 8)];
                const bf16x8 a1 = *(const bf16x8*)&sp[pix(arw, 32 + lq * 8)];
                #pragma unroll
                for (int ni = 0; ni < 4; ni++) {
                    const int d = ni * 16 + lc;
                    const bf16x8 b0 = *(const bf16x8*)&xt[xix(d, lq * 8)];
                    const bf16x8 b1 = *(const bf16x8*)&xt[xix(d, 32 + lq * 8)];
                    oa[ni] = __builtin_amdgcn_mfma_f32_16x16x32_bf16(a0, b0, oa[ni], 0, 0, 0);
                    oa[ni] = __builtin_amdgcn_mfma_f32_16x16x32_bf16(a1, b1, oa[ni], 0, 0, 0);
                }
            }
            // ---- (b) write O in place over q (rows < 49 only) ----
            #pragma unroll
            for (int rg = 0; rg < 4; rg++) {
                const int i = tv * 16 + lq * 4 + rg;
                if (i < WW) {
                    #pragma unroll
                    for (int ni = 0; ni < 4; ni++)
                        q_s[qix(r * WW + i, c0 + ni * 16 + lc)] = f2bf(oa[ni][rg]);
                }
            }
            __syncthreads();   // buffers reusable; q_s consistent for next round
        }
    }

    // ================= Phase 3: out = O @ Wo^T + bo =================
    {
        const short* br[8];
        #pragma unroll
        for (int ni = 0; ni < 8; ni++)
            br[ni] = Wob + (size_t)(wn + ni * 16 + lc) * DM + lq * 8;
        int lr[4];
        #pragma unroll
        for (int mi = 0; mi < 4; mi++) {
            int t = wm + mi * 16 + lc;
            t = (t > SEG - 1) ? (SEG - 1) : t;
            lr[mi] = (t % RD) * WW + t / RD;
        }
        f32x4 acc[4][8] = {};
        for (int k0 = 0; k0 < DM; k0 += 32) {
            bf16x8 af[4], bfr[8];
            #pragma unroll
            for (int mi = 0; mi < 4; mi++)
                af[mi] = *(const bf16x8*)&q_s[qix(lr[mi], k0 + lq * 8)];
            #pragma unroll
            for (int ni = 0; ni < 8; ni++) bfr[ni] = *(const bf16x8*)(br[ni] + k0);
            #pragma unroll
            for (int mi = 0; mi < 4; mi++)
                #pragma unroll
                for (int ni = 0; ni < 8; ni++)
                    acc[mi][ni] = __builtin_amdgcn_mfma_f32_16x16x32_bf16(
                        af[mi], bfr[ni], acc[mi][ni], 0, 0, 0);
        }
        float bv[8];
        #pragma unroll
        for (int ni = 0; ni < 8; ni++) bv[ni] = bo[wn + ni * 16 + lc];
        #pragma unroll
        for (int mi = 0; mi < 4; mi++)
            #pragma unroll
            for (int rg = 0; rg < 4; rg++) {
                const int t = wm + mi * 16 + lq * 4 + rg;
                if (t < SEG) {
                    float* op = out + ebase + (size_t)t * DM;
                    #pragma unroll
                    for (int ni = 0; ni < 8; ni++)
                        op[wn + ni * 16 + lc] = acc[mi][ni][rg] + bv[ni];
                }
            }
    }
}

// ---------------------------------------------------------------------------
extern "C" void kernel_launch(void* const* d_in, const int* in_sizes, int n_in,
                              void* d_out, int out_size, void* d_ws, size_t ws_size,
                              hipStream_t stream) {
    const float* emb = (const float*)d_in[0];
    const float* Wq  = (const float*)d_in[1];
    const float* bq  = (const float*)d_in[2];
    const float* Wo  = (const float*)d_in[3];
    const float* bo  = (const float*)d_in[4];
    float* out = (float*)d_out;

    // Workspace: Wq bf16 (128 KB) | Wo bf16 (128 KB)
    short* Wqb = (short*)d_ws;
    short* Wob = Wqb + DM * DM;

    wcvt<<<dim3(128), dim3(256), 0, stream>>>(Wq, Wo, Wqb, Wob);
    fused<<<dim3(BATCH * GSEG), dim3(512), 0, stream>>>(emb, Wqb, bq, Wob, bo, out);
}